// Round 1
// baseline (1173.215 us; speedup 1.0000x reference)
//
#include <hip/hip_runtime.h>
#include <math.h>

// ---------------------------------------------------------------------------
// RoutingNet: 5x (conv3x3 + BN + ReLU + maxpool2x2) -> feats(250,256)
//   e = sup @ trans_w.T + trans_b ; 3-iter routing -> proto(10,256)
//   t1 = einsum(proto, bil_w) ; v = t1 . q ; s = relu(v)@score_w ; log_softmax
// Round 1: correctness-first, simple fp32 kernels. Optimize with profile next.
// ---------------------------------------------------------------------------

// Block 0: 1->16 ch, 128x128 -> conv s2 -> 64x64 -> pool -> 32x32
__global__ void k_block0(const float* __restrict__ sup, const float* __restrict__ qry,
                         const float* __restrict__ w, const float* __restrict__ g,
                         const float* __restrict__ bb, float* __restrict__ out) {
  int idx = blockIdx.x * 256 + threadIdx.x;   // 250*16*32*32 = 4,096,000 exact
  int ox = idx & 31; int t = idx >> 5;
  int oy = t & 31; t >>= 5;
  int oc = t & 15; int img = t >> 4;
  const float* in = (img < 100) ? (sup + (size_t)img * 16384)
                                : (qry + (size_t)(img - 100) * 16384);
  float scale = g[oc] * rsqrtf(1.0f + 1e-5f);
  float bias = bb[oc];
  float wv[9];
#pragma unroll
  for (int i = 0; i < 9; i++) wv[i] = w[oc * 9 + i];
  float m = -1e30f;
#pragma unroll
  for (int py = 0; py < 2; py++)
#pragma unroll
    for (int px = 0; px < 2; px++) {
      int cy = 2 * oy + py, cx = 2 * ox + px;   // conv coords in 64x64
      float acc = 0.f;
#pragma unroll
      for (int ky = 0; ky < 3; ky++) {
        int iy = 2 * cy - 1 + ky;
        if (iy < 0 || iy >= 128) continue;
#pragma unroll
        for (int kx = 0; kx < 3; kx++) {
          int ix = 2 * cx - 1 + kx;
          if (ix < 0 || ix >= 128) continue;
          acc = fmaf(in[iy * 128 + ix], wv[ky * 3 + kx], acc);
        }
      }
      m = fmaxf(m, fmaf(acc, scale, bias));
    }
  out[idx] = fmaxf(m, 0.f);   // relu after max == max after relu
}

// Generic block: IC->OC, IHW x IHW input, conv stride S pad 1, pool 2x2 -> PHW
template <int IC, int OC, int IHW, int S, int PHW>
__global__ void k_block(const float* __restrict__ xin, const float* __restrict__ w,
                        const float* __restrict__ g, const float* __restrict__ bb,
                        float* __restrict__ out) {
  int idx = blockIdx.x * 256 + threadIdx.x;   // 250*OC*PHW*PHW, exact multiple of 256
  int ox = idx % PHW; int t = idx / PHW;
  int oy = t % PHW; t /= PHW;
  int oc = t % OC; int img = t / OC;
  const float* in = xin + (size_t)img * IC * IHW * IHW;
  const float* wp = w + (size_t)oc * IC * 9;
  float scale = g[oc] * rsqrtf(1.0f + 1e-5f);
  float bias = bb[oc];
  float m = -1e30f;
#pragma unroll
  for (int py = 0; py < 2; py++)
#pragma unroll
    for (int px = 0; px < 2; px++) {
      int cy = 2 * oy + py, cx = 2 * ox + px;
      float acc = 0.f;
      for (int ic = 0; ic < IC; ic++) {
        const float* ip = in + ic * IHW * IHW;
        const float* wpp = wp + ic * 9;
#pragma unroll
        for (int ky = 0; ky < 3; ky++) {
          int iy = S * cy - 1 + ky;
          if (iy < 0 || iy >= IHW) continue;
#pragma unroll
          for (int kx = 0; kx < 3; kx++) {
            int ix = S * cx - 1 + kx;
            if (ix < 0 || ix >= IHW) continue;
            acc = fmaf(ip[iy * IHW + ix], wpp[ky * 3 + kx], acc);
          }
        }
      }
      m = fmaxf(m, fmaf(acc, scale, bias));
    }
  out[idx] = fmaxf(m, 0.f);
}

// e[nk, c] = dot(feats[nk,:], trans_w[c,:]) + trans_b[c]
__global__ void k_e(const float* __restrict__ feats, const float* __restrict__ tw,
                    const float* __restrict__ tb, float* __restrict__ e) {
  int nk = blockIdx.x;     // 0..99
  int c = threadIdx.x;     // 0..255
  __shared__ float sf[256];
  sf[c] = feats[nk * 256 + c];
  __syncthreads();
  const float4* a = (const float4*)(tw + (size_t)c * 256);
  const float4* b = (const float4*)sf;
  float acc = tb[c];
  for (int d = 0; d < 64; d++) {
    float4 x = a[d], y = b[d];
    acc += x.x * y.x + x.y * y.y + x.z * y.z + x.w * y.w;
  }
  e[nk * 256 + c] = acc;
}

// 3-iter routing; one block per n (10 blocks), 256 threads (thread = feature dim d)
__global__ void k_routing(const float* __restrict__ e, float* __restrict__ proto) {
  int n = blockIdx.x;
  __shared__ float se[10 * 256];
  __shared__ float sb[10], sdc[10];
  __shared__ float red[8];
  int t = threadIdx.x;
  int lane = t & 63, wid = t >> 6;
  for (int i = t; i < 2560; i += 256) se[i] = e[n * 2560 + i];
  if (t < 10) sb[t] = 0.f;
  __syncthreads();
  float cd = 0.f;
  for (int iter = 0; iter < 3; iter++) {
    if (t == 0) {  // softmax over k (10 values) — tiny, serial
      float mx = sb[0];
      for (int k = 1; k < 10; k++) mx = fmaxf(mx, sb[k]);
      float sum = 0.f;
      for (int k = 0; k < 10; k++) { float ex = expf(sb[k] - mx); sdc[k] = ex; sum += ex; }
      float inv = 1.f / sum;
      for (int k = 0; k < 10; k++) sdc[k] *= inv;
    }
    __syncthreads();
    cd = 0.f;
    for (int k = 0; k < 10; k++) cd = fmaf(sdc[k], se[k * 256 + t], cd);
    // squash: factor = ||c|| / (||c||^2 + 1)
    float ss = cd * cd;
#pragma unroll
    for (int off = 32; off > 0; off >>= 1) ss += __shfl_down(ss, off, 64);
    if (lane == 0) red[wid] = ss;
    __syncthreads();
    if (t == 0) {
      float tot = red[0] + red[1] + red[2] + red[3];
      red[4] = sqrtf(tot) / (tot + 1.f);
    }
    __syncthreads();
    cd *= red[4];
    __syncthreads();
    // db[k] = dot(c, e[k]); b += db
    for (int k = 0; k < 10; k++) {
      float p = cd * se[k * 256 + t];
#pragma unroll
      for (int off = 32; off > 0; off >>= 1) p += __shfl_down(p, off, 64);
      if (lane == 0) red[wid] = p;
      __syncthreads();
      if (t == 0) sb[k] += red[0] + red[1] + red[2] + red[3];
      __syncthreads();
    }
  }
  proto[n * 256 + t] = cd;
}

// t1[n,h,e] = sum_c proto[n,c] * bil_w[h,c,e]; one block per h, thread = e
__global__ void k_t1(const float* __restrict__ proto, const float* __restrict__ bw,
                     float* __restrict__ t1) {
  int h = blockIdx.x;     // 0..99
  int e = threadIdx.x;    // 0..255
  __shared__ float sp[2560];
  for (int i = e; i < 2560; i += 256) sp[i] = proto[i];
  __syncthreads();
  float acc[10];
#pragma unroll
  for (int n = 0; n < 10; n++) acc[n] = 0.f;
  const float* w = bw + (size_t)h * 65536;
  for (int c = 0; c < 256; c++) {
    float wv = w[c * 256 + e];   // coalesced across threads
#pragma unroll
    for (int n = 0; n < 10; n++) acc[n] = fmaf(sp[n * 256 + c], wv, acc[n]);
  }
#pragma unroll
  for (int n = 0; n < 10; n++) t1[((size_t)n * 100 + h) * 256 + e] = acc[n];
}

// s[q,n] = sum_h relu(dot(t1[n,h,:], qf[q,:])) * sw[h] + sb
// one block per (q,n): 1500 blocks, each wave handles 25 h values
__global__ void k_score(const float* __restrict__ t1, const float* __restrict__ qf,
                        const float* __restrict__ sw, const float* __restrict__ sbp,
                        float* __restrict__ s) {
  int q = blockIdx.x / 10, n = blockIdx.x % 10;
  int t = threadIdx.x, lane = t & 63, wid = t >> 6;
  float qv[4];
#pragma unroll
  for (int j = 0; j < 4; j++) qv[j] = qf[q * 256 + j * 64 + lane];
  const float* tn = t1 + (size_t)n * 100 * 256;
  float acc = 0.f;
  for (int h = wid * 25; h < wid * 25 + 25; h++) {
    float p = 0.f;
#pragma unroll
    for (int j = 0; j < 4; j++) p = fmaf(tn[h * 256 + j * 64 + lane], qv[j], p);
#pragma unroll
    for (int off = 32; off > 0; off >>= 1) p += __shfl_down(p, off, 64);
    if (lane == 0) acc = fmaf(fmaxf(p, 0.f), sw[h], acc);
  }
  __shared__ float r[4];
  if (lane == 0) r[wid] = acc;
  __syncthreads();
  if (t == 0) s[q * 10 + n] = r[0] + r[1] + r[2] + r[3] + sbp[0];
}

// out[q,:] = s[q,:] - logsumexp(s[q,:])
__global__ void k_lsm(const float* __restrict__ s, float* __restrict__ out) {
  int q = blockIdx.x * 256 + threadIdx.x;
  if (q >= 150) return;
  float mx = -1e30f;
  for (int n = 0; n < 10; n++) mx = fmaxf(mx, s[q * 10 + n]);
  float sum = 0.f;
  for (int n = 0; n < 10; n++) sum += expf(s[q * 10 + n] - mx);
  float lse = mx + logf(sum);
  for (int n = 0; n < 10; n++) out[q * 10 + n] = s[q * 10 + n] - lse;
}

extern "C" void kernel_launch(void* const* d_in, const int* in_sizes, int n_in,
                              void* d_out, int out_size, void* d_ws, size_t ws_size,
                              hipStream_t stream) {
  const float* support = (const float*)d_in[0];
  const float* query   = (const float*)d_in[1];
  const float* conv_w[5]; const float* bn_g[5]; const float* bn_b[5];
  for (int i = 0; i < 5; i++) {
    conv_w[i] = (const float*)d_in[2 + 3 * i];
    bn_g[i]   = (const float*)d_in[3 + 3 * i];
    bn_b[i]   = (const float*)d_in[4 + 3 * i];
  }
  const float* trans_w = (const float*)d_in[17];
  const float* trans_b = (const float*)d_in[18];
  const float* bil_w   = (const float*)d_in[19];
  const float* score_w = (const float*)d_in[20];
  const float* score_b = (const float*)d_in[21];
  float* out = (float*)d_out;
  float* ws = (float*)d_ws;

  // workspace layout (floats): ~21.4 MB total
  float* buf1  = ws;                 // (250,16,32,32) = 4,096,000
  float* buf2  = buf1 + 4096000;     // (250,32,8,8)   =   512,000
  float* buf3  = buf2 + 512000;      // (250,64,4,4)   =   256,000
  float* buf4  = buf3 + 256000;      // (250,128,2,2)  =   128,000
  float* feats = buf4 + 128000;      // (250,256)      =    64,000
  float* e_buf = feats + 64000;      // (10,10,256)    =    25,600
  float* proto = e_buf + 25600;      // (10,256)       =     2,560
  float* t1    = proto + 2560;       // (10,100,256)   =   256,000
  float* s_buf = t1 + 256000;        // (150,10)       =     1,500

  k_block0<<<16000, 256, 0, stream>>>(support, query, conv_w[0], bn_g[0], bn_b[0], buf1);
  k_block<16, 32, 32, 2, 8><<<2000, 256, 0, stream>>>(buf1, conv_w[1], bn_g[1], bn_b[1], buf2);
  k_block<32, 64, 8, 1, 4><<<1000, 256, 0, stream>>>(buf2, conv_w[2], bn_g[2], bn_b[2], buf3);
  k_block<64, 128, 4, 1, 2><<<500, 256, 0, stream>>>(buf3, conv_w[3], bn_g[3], bn_b[3], buf4);
  k_block<128, 256, 2, 1, 1><<<250, 256, 0, stream>>>(buf4, conv_w[4], bn_g[4], bn_b[4], feats);
  k_e<<<100, 256, 0, stream>>>(feats, trans_w, trans_b, e_buf);
  k_routing<<<10, 256, 0, stream>>>(e_buf, proto);
  k_t1<<<100, 256, 0, stream>>>(proto, bil_w, t1);
  k_score<<<1500, 256, 0, stream>>>(t1, feats + 100 * 256, score_w, score_b, s_buf);
  k_lsm<<<1, 256, 0, stream>>>(s_buf, out);
}

// Round 2
// 349.296 us; speedup vs baseline: 3.3588x; 3.3588x over previous
//
#include <hip/hip_runtime.h>
#include <math.h>

// ---------------------------------------------------------------------------
// RoutingNet round 2: LDS-staged convs, one workgroup per image (or band),
// fused blocks 2-4, transposed weights for coalesced per-oc loads.
// ---------------------------------------------------------------------------

#define BN_SCALE rsqrtf(1.0f + 1e-5f)

// Transpose conv weights OIHW -> [ic][tap][oc] for layers 2,3,4.
// 18432 + 73728 + 294912 = 387072 = 1512 * 256 elements.
__global__ void k_transpose(const float* __restrict__ w2, const float* __restrict__ w3,
                            const float* __restrict__ w4, float* __restrict__ w2t,
                            float* __restrict__ w3t, float* __restrict__ w4t) {
  int i = blockIdx.x * 256 + threadIdx.x;
  if (i < 18432) {                       // w2: OC=64, IC=32
    int oc = i & 63; int r = i >> 6; int tap = r % 9; int ic = r / 9;
    w2t[i] = w2[(oc * 32 + ic) * 9 + tap];
  } else if (i < 18432 + 73728) {        // w3: OC=128, IC=64
    int j = i - 18432;
    int oc = j & 127; int r = j >> 7; int tap = r % 9; int ic = r / 9;
    w3t[j] = w3[(oc * 64 + ic) * 9 + tap];
  } else {                               // w4: OC=256, IC=128
    int j = i - 18432 - 73728;
    int oc = j & 255; int r = j >> 8; int tap = r % 9; int ic = r / 9;
    w4t[j] = w4[(oc * 128 + ic) * 9 + tap];
  }
}

// Block 0: 1->16ch, 128x128 -s2-> 64x64 -pool-> 32x32.
// Grid 1000: blockIdx = img*4 + band. Band = 8 pooled rows.
__global__ void k_block0(const float* __restrict__ sup, const float* __restrict__ qry,
                         const float* __restrict__ w, const float* __restrict__ g,
                         const float* __restrict__ bb, float* __restrict__ out) {
  __shared__ float simg[33 * 128];   // 16.9 KB: input rows band*32-1 .. band*32+31
  int img = blockIdx.x >> 2, band = blockIdx.x & 3;
  const float* in = (img < 100) ? (sup + (size_t)img * 16384)
                                : (qry + (size_t)(img - 100) * 16384);
  int t = threadIdx.x;
  int row0 = band * 32 - 1;
  for (int i = t; i < 33 * 128; i += 256) {
    int r = i >> 7, cc = i & 127;
    int ry = row0 + r;
    simg[i] = (ry >= 0) ? in[ry * 128 + cc] : 0.f;   // ry <= 127 always
  }
  __syncthreads();

  int lane = t & 63, wid = t >> 6;
  int ox = lane & 31, oyh = lane >> 5;      // 32 cols x 2 row-parity
  int oc0 = wid * 4;
  float wv[36], sc[4], bs[4];
#pragma unroll
  for (int j = 0; j < 4; j++) {
#pragma unroll
    for (int k = 0; k < 9; k++) wv[j * 9 + k] = w[(oc0 + j) * 9 + k];
    sc[j] = g[oc0 + j] * BN_SCALE;
    bs[j] = bb[oc0 + j];
  }
#pragma unroll
  for (int oyy = 0; oyy < 4; oyy++) {
    int oy = oyy * 2 + oyh;                 // local pooled row 0..7
    float win[25];
#pragma unroll
    for (int d = 0; d < 5; d++) {
      int lr = 4 * oy + d;                  // LDS row (already offset by -1)
#pragma unroll
      for (int e = 0; e < 5; e++) {
        int cx = 4 * ox - 1 + e;
        win[d * 5 + e] = (cx >= 0) ? simg[lr * 128 + cx] : 0.f;  // cx <= 127 always
      }
    }
#pragma unroll
    for (int j = 0; j < 4; j++) {
      float m = -1e30f;
#pragma unroll
      for (int py = 0; py < 2; py++)
#pragma unroll
        for (int px = 0; px < 2; px++) {
          float c = 0.f;
#pragma unroll
          for (int ky = 0; ky < 3; ky++)
#pragma unroll
            for (int kx = 0; kx < 3; kx++)
              c = fmaf(win[(2 * py + ky) * 5 + (2 * px + kx)], wv[j * 9 + ky * 3 + kx], c);
          m = fmaxf(m, fmaf(c, sc[j], bs[j]));
        }
      int OY = band * 8 + oy;
      out[(((size_t)img * 16 + oc0 + j) * 32 + OY) * 32 + ox] = fmaxf(m, 0.f);
    }
  }
}

// Block 1: 16->32ch, 32x32 -s2-> 16x16 -pool-> 8x8. One workgroup per image.
__global__ void k_block1(const float* __restrict__ a0, const float* __restrict__ w,
                         const float* __restrict__ g, const float* __restrict__ bb,
                         float* __restrict__ out) {
  __shared__ float sa[16 * 32 * 32];   // 64 KB
  int img = blockIdx.x;
  int t = threadIdx.x;
  const float4* src = (const float4*)(a0 + (size_t)img * 16384);
  float4* dst = (float4*)sa;
  for (int i = t; i < 4096; i += 256) dst[i] = src[i];
  __syncthreads();

  int lane = t & 63, wid = t >> 6;
  int ox = lane & 7, oy = lane >> 3;   // 8x8 pooled positions
  int oc0 = wid * 8;
  float acc[8][4];
#pragma unroll
  for (int j = 0; j < 8; j++)
#pragma unroll
    for (int p = 0; p < 4; p++) acc[j][p] = 0.f;

  for (int ic = 0; ic < 16; ic++) {
    const float* base = sa + ic * 1024;
    float win[25];
#pragma unroll
    for (int d = 0; d < 5; d++) {
      int r = 4 * oy - 1 + d;
#pragma unroll
      for (int e = 0; e < 5; e++) {
        int c = 4 * ox - 1 + e;
        win[d * 5 + e] = (r >= 0 && c >= 0) ? base[r * 32 + c] : 0.f;  // r,c <= 31 always
      }
    }
#pragma unroll
    for (int j = 0; j < 8; j++) {
      const float* wp = w + ((size_t)(oc0 + j) * 16 + ic) * 9;
      float w0 = wp[0], w1 = wp[1], w2 = wp[2], w3 = wp[3], w4 = wp[4],
            w5 = wp[5], w6 = wp[6], w7 = wp[7], w8 = wp[8];
#pragma unroll
      for (int py = 0; py < 2; py++)
#pragma unroll
        for (int px = 0; px < 2; px++) {
          float c = acc[j][py * 2 + px];
          c = fmaf(win[(2 * py + 0) * 5 + 2 * px + 0], w0, c);
          c = fmaf(win[(2 * py + 0) * 5 + 2 * px + 1], w1, c);
          c = fmaf(win[(2 * py + 0) * 5 + 2 * px + 2], w2, c);
          c = fmaf(win[(2 * py + 1) * 5 + 2 * px + 0], w3, c);
          c = fmaf(win[(2 * py + 1) * 5 + 2 * px + 1], w4, c);
          c = fmaf(win[(2 * py + 1) * 5 + 2 * px + 2], w5, c);
          c = fmaf(win[(2 * py + 2) * 5 + 2 * px + 0], w6, c);
          c = fmaf(win[(2 * py + 2) * 5 + 2 * px + 1], w7, c);
          c = fmaf(win[(2 * py + 2) * 5 + 2 * px + 2], w8, c);
          acc[j][py * 2 + px] = c;
        }
    }
  }
#pragma unroll
  for (int j = 0; j < 8; j++) {
    float sc = g[oc0 + j] * BN_SCALE, bsj = bb[oc0 + j];
    float m = -1e30f;
#pragma unroll
    for (int p = 0; p < 4; p++) m = fmaxf(m, fmaf(acc[j][p], sc, bsj));
    out[(((size_t)img * 32 + oc0 + j) * 8 + oy) * 8 + ox] = fmaxf(m, 0.f);
  }
}

// Blocks 2+3+4 fused, one workgroup per image. Intermediates in LDS.
// a1(32,8,8) -> a2(64,4,4) -> a3(128,2,2) -> feats(256)
__global__ void k_conv234(const float* __restrict__ a1g,
                          const float* __restrict__ w2t, const float* __restrict__ g2, const float* __restrict__ b2,
                          const float* __restrict__ w3t, const float* __restrict__ g3, const float* __restrict__ b3,
                          const float* __restrict__ w4t, const float* __restrict__ g4, const float* __restrict__ b4,
                          float* __restrict__ feats) {
  __shared__ float sA[32 * 10 * 10];   // a1 padded  (12.8 KB)
  __shared__ float sB[64 * 6 * 6];     // a2 padded  (9.2 KB)
  __shared__ float sC[128 * 2 * 2];    // a3 unpadded (2 KB)
  int img = blockIdx.x;
  int t = threadIdx.x;

  for (int i = t; i < 3200; i += 256) sA[i] = 0.f;
  for (int i = t; i < 2304; i += 256) sB[i] = 0.f;
  __syncthreads();
  const float* a1 = a1g + (size_t)img * 2048;
  for (int i = t; i < 2048; i += 256) {
    int ic = i >> 6, y = (i >> 3) & 7, x = i & 7;
    sA[ic * 100 + (y + 1) * 10 + (x + 1)] = a1[i];
  }
  __syncthreads();

  // ---- layer 2: 32->64, 8x8 -> conv 8x8 -> pool 4x4 ----
  {
    int pos = t & 15, ocg = t >> 4;
    int oy = pos >> 2, ox = pos & 3;
    int oc0 = ocg * 4;
    float acc[4][4];
#pragma unroll
    for (int j = 0; j < 4; j++)
#pragma unroll
      for (int p = 0; p < 4; p++) acc[j][p] = 0.f;
    for (int ic = 0; ic < 32; ic++) {
      const float* base = sA + ic * 100 + 2 * oy * 10 + 2 * ox;
      float win[16];
#pragma unroll
      for (int d = 0; d < 4; d++)
#pragma unroll
        for (int e = 0; e < 4; e++) win[d * 4 + e] = base[d * 10 + e];
#pragma unroll
      for (int j = 0; j < 4; j++) {
        const float* wp = w2t + (size_t)ic * 9 * 64 + (oc0 + j);
        float wr[9];
#pragma unroll
        for (int k = 0; k < 9; k++) wr[k] = wp[k * 64];
#pragma unroll
        for (int py = 0; py < 2; py++)
#pragma unroll
          for (int px = 0; px < 2; px++) {
            float c = acc[j][py * 2 + px];
#pragma unroll
            for (int ky = 0; ky < 3; ky++)
#pragma unroll
              for (int kx = 0; kx < 3; kx++)
                c = fmaf(win[(py + ky) * 4 + (px + kx)], wr[ky * 3 + kx], c);
            acc[j][py * 2 + px] = c;
          }
      }
    }
#pragma unroll
    for (int j = 0; j < 4; j++) {
      int oc = oc0 + j;
      float sc = g2[oc] * BN_SCALE, bsj = b2[oc];
      float m = -1e30f;
#pragma unroll
      for (int p = 0; p < 4; p++) m = fmaxf(m, fmaf(acc[j][p], sc, bsj));
      sB[oc * 36 + (oy + 1) * 6 + (ox + 1)] = fmaxf(m, 0.f);
    }
  }
  __syncthreads();

  // ---- layer 3: 64->128, 4x4 -> conv 4x4 -> pool 2x2 ----
  {
    int pos = t & 3, ocg = t >> 2;
    int oy = pos >> 1, ox = pos & 1;
    int oc0 = ocg * 2;
    float acc[2][4];
#pragma unroll
    for (int j = 0; j < 2; j++)
#pragma unroll
      for (int p = 0; p < 4; p++) acc[j][p] = 0.f;
    for (int ic = 0; ic < 64; ic++) {
      const float* base = sB + ic * 36 + 2 * oy * 6 + 2 * ox;
      float win[16];
#pragma unroll
      for (int d = 0; d < 4; d++)
#pragma unroll
        for (int e = 0; e < 4; e++) win[d * 4 + e] = base[d * 6 + e];
#pragma unroll
      for (int j = 0; j < 2; j++) {
        const float* wp = w3t + (size_t)ic * 9 * 128 + (oc0 + j);
        float wr[9];
#pragma unroll
        for (int k = 0; k < 9; k++) wr[k] = wp[k * 128];
#pragma unroll
        for (int py = 0; py < 2; py++)
#pragma unroll
          for (int px = 0; px < 2; px++) {
            float c = acc[j][py * 2 + px];
#pragma unroll
            for (int ky = 0; ky < 3; ky++)
#pragma unroll
              for (int kx = 0; kx < 3; kx++)
                c = fmaf(win[(py + ky) * 4 + (px + kx)], wr[ky * 3 + kx], c);
            acc[j][py * 2 + px] = c;
          }
      }
    }
#pragma unroll
    for (int j = 0; j < 2; j++) {
      int oc = oc0 + j;
      float sc = g3[oc] * BN_SCALE, bsj = b3[oc];
      float m = -1e30f;
#pragma unroll
      for (int p = 0; p < 4; p++) m = fmaxf(m, fmaf(acc[j][p], sc, bsj));
      sC[oc * 4 + oy * 2 + ox] = fmaxf(m, 0.f);
    }
  }
  __syncthreads();

  // ---- layer 4: 128->256, 2x2 -> conv 2x2 (pad) -> pool 1x1 ----
  {
    int oc = t;
    float acc[4];
#pragma unroll
    for (int p = 0; p < 4; p++) acc[p] = 0.f;
    for (int ic = 0; ic < 128; ic++) {
      float i00 = sC[ic * 4 + 0], i01 = sC[ic * 4 + 1];
      float i10 = sC[ic * 4 + 2], i11 = sC[ic * 4 + 3];
      const float* wp = w4t + (size_t)ic * 9 * 256 + oc;
      float wr[9];
#pragma unroll
      for (int k = 0; k < 9; k++) wr[k] = wp[k * 256];
      // conv pos (py,px): acc += in(iy,ix) * w[(iy+1-py)*3 + (ix+1-px)]
#pragma unroll
      for (int py = 0; py < 2; py++)
#pragma unroll
        for (int px = 0; px < 2; px++) {
          float c = acc[py * 2 + px];
          c = fmaf(i00, wr[(1 - py) * 3 + (1 - px)], c);
          c = fmaf(i01, wr[(1 - py) * 3 + (2 - px)], c);
          c = fmaf(i10, wr[(2 - py) * 3 + (1 - px)], c);
          c = fmaf(i11, wr[(2 - py) * 3 + (2 - px)], c);
          acc[py * 2 + px] = c;
        }
    }
    float sc = g4[oc] * BN_SCALE, bsj = b4[oc];
    float m = -1e30f;
#pragma unroll
    for (int p = 0; p < 4; p++) m = fmaxf(m, fmaf(acc[p], sc, bsj));
    feats[(size_t)img * 256 + oc] = fmaxf(m, 0.f);
  }
}

// e[nk, c] = dot(feats[nk,:], trans_w[c,:]) + trans_b[c]
__global__ void k_e(const float* __restrict__ feats, const float* __restrict__ tw,
                    const float* __restrict__ tb, float* __restrict__ e) {
  int nk = blockIdx.x;
  int c = threadIdx.x;
  __shared__ float sf[256];
  sf[c] = feats[nk * 256 + c];
  __syncthreads();
  const float4* a = (const float4*)(tw + (size_t)c * 256);
  const float4* b = (const float4*)sf;
  float acc = tb[c];
  for (int d = 0; d < 64; d++) {
    float4 x = a[d], y = b[d];
    acc += x.x * y.x + x.y * y.y + x.z * y.z + x.w * y.w;
  }
  e[nk * 256 + c] = acc;
}

// 3-iter routing; one block per n (10 blocks)
__global__ void k_routing(const float* __restrict__ e, float* __restrict__ proto) {
  int n = blockIdx.x;
  __shared__ float se[10 * 256];
  __shared__ float sb[10], sdc[10];
  __shared__ float red[8];
  int t = threadIdx.x;
  int lane = t & 63, wid = t >> 6;
  for (int i = t; i < 2560; i += 256) se[i] = e[n * 2560 + i];
  if (t < 10) sb[t] = 0.f;
  __syncthreads();
  float cd = 0.f;
  for (int iter = 0; iter < 3; iter++) {
    if (t == 0) {
      float mx = sb[0];
      for (int k = 1; k < 10; k++) mx = fmaxf(mx, sb[k]);
      float sum = 0.f;
      for (int k = 0; k < 10; k++) { float ex = expf(sb[k] - mx); sdc[k] = ex; sum += ex; }
      float inv = 1.f / sum;
      for (int k = 0; k < 10; k++) sdc[k] *= inv;
    }
    __syncthreads();
    cd = 0.f;
    for (int k = 0; k < 10; k++) cd = fmaf(sdc[k], se[k * 256 + t], cd);
    float ss = cd * cd;
#pragma unroll
    for (int off = 32; off > 0; off >>= 1) ss += __shfl_down(ss, off, 64);
    if (lane == 0) red[wid] = ss;
    __syncthreads();
    if (t == 0) {
      float tot = red[0] + red[1] + red[2] + red[3];
      red[4] = sqrtf(tot) / (tot + 1.f);
    }
    __syncthreads();
    cd *= red[4];
    __syncthreads();
    for (int k = 0; k < 10; k++) {
      float p = cd * se[k * 256 + t];
#pragma unroll
      for (int off = 32; off > 0; off >>= 1) p += __shfl_down(p, off, 64);
      if (lane == 0) red[wid] = p;
      __syncthreads();
      if (t == 0) sb[k] += red[0] + red[1] + red[2] + red[3];
      __syncthreads();
    }
  }
  proto[n * 256 + t] = cd;
}

// t1[n,h,e] = sum_c proto[n,c] * bil_w[h,c,e]
__global__ void k_t1(const float* __restrict__ proto, const float* __restrict__ bw,
                     float* __restrict__ t1) {
  int h = blockIdx.x;
  int e = threadIdx.x;
  __shared__ float sp[2560];
  for (int i = e; i < 2560; i += 256) sp[i] = proto[i];
  __syncthreads();
  float acc[10];
#pragma unroll
  for (int n = 0; n < 10; n++) acc[n] = 0.f;
  const float* w = bw + (size_t)h * 65536;
#pragma unroll 4
  for (int c = 0; c < 256; c++) {
    float wv = w[c * 256 + e];
#pragma unroll
    for (int n = 0; n < 10; n++) acc[n] = fmaf(sp[n * 256 + c], wv, acc[n]);
  }
#pragma unroll
  for (int n = 0; n < 10; n++) t1[((size_t)n * 100 + h) * 256 + e] = acc[n];
}

// s[q,n] = sum_h relu(dot(t1[n,h,:], qf[q,:])) * sw[h] + sb
__global__ void k_score(const float* __restrict__ t1, const float* __restrict__ qf,
                        const float* __restrict__ sw, const float* __restrict__ sbp,
                        float* __restrict__ s) {
  int q = blockIdx.x / 10, n = blockIdx.x % 10;
  int t = threadIdx.x, lane = t & 63, wid = t >> 6;
  float qv[4];
#pragma unroll
  for (int j = 0; j < 4; j++) qv[j] = qf[q * 256 + j * 64 + lane];
  const float* tn = t1 + (size_t)n * 100 * 256;
  float acc = 0.f;
  for (int h = wid * 25; h < wid * 25 + 25; h++) {
    float p = 0.f;
#pragma unroll
    for (int j = 0; j < 4; j++) p = fmaf(tn[h * 256 + j * 64 + lane], qv[j], p);
#pragma unroll
    for (int off = 32; off > 0; off >>= 1) p += __shfl_down(p, off, 64);
    if (lane == 0) acc = fmaf(fmaxf(p, 0.f), sw[h], acc);
  }
  __shared__ float r[4];
  if (lane == 0) r[wid] = acc;
  __syncthreads();
  if (t == 0) s[q * 10 + n] = r[0] + r[1] + r[2] + r[3] + sbp[0];
}

__global__ void k_lsm(const float* __restrict__ s, float* __restrict__ out) {
  int q = blockIdx.x * 256 + threadIdx.x;
  if (q >= 150) return;
  float mx = -1e30f;
  for (int n = 0; n < 10; n++) mx = fmaxf(mx, s[q * 10 + n]);
  float sum = 0.f;
  for (int n = 0; n < 10; n++) sum += expf(s[q * 10 + n] - mx);
  float lse = mx + logf(sum);
  for (int n = 0; n < 10; n++) out[q * 10 + n] = s[q * 10 + n] - lse;
}

extern "C" void kernel_launch(void* const* d_in, const int* in_sizes, int n_in,
                              void* d_out, int out_size, void* d_ws, size_t ws_size,
                              hipStream_t stream) {
  const float* support = (const float*)d_in[0];
  const float* query   = (const float*)d_in[1];
  const float* conv_w[5]; const float* bn_g[5]; const float* bn_b[5];
  for (int i = 0; i < 5; i++) {
    conv_w[i] = (const float*)d_in[2 + 3 * i];
    bn_g[i]   = (const float*)d_in[3 + 3 * i];
    bn_b[i]   = (const float*)d_in[4 + 3 * i];
  }
  const float* trans_w = (const float*)d_in[17];
  const float* trans_b = (const float*)d_in[18];
  const float* bil_w   = (const float*)d_in[19];
  const float* score_w = (const float*)d_in[20];
  const float* score_b = (const float*)d_in[21];
  float* out = (float*)d_out;
  float* ws = (float*)d_ws;

  // persistent regions
  float* a0    = ws;                 // (250,16,32,32) = 4,096,000
  float* a1    = a0 + 4096000;       // (250,32,8,8)   =   512,000
  float* feats = a1 + 512000;        // (250,256)      =    64,000
  float* w2t   = feats + 64000;      //                =    18,432
  float* w3t   = w2t + 18432;        //                =    73,728
  float* w4t   = w3t + 73728;        //                =   294,912
  // aliased into a0 (a0 dead after k_block1 completes):
  float* e_buf = a0;                 // (100,256) = 25,600
  float* proto = a0 + 25600;         // (10,256)  =  2,560
  float* t1    = a0 + 28160;         // (10,100,256) = 256,000
  float* s_buf = a0 + 284160;        // (150,10)  =  1,500

  k_transpose<<<1512, 256, 0, stream>>>(conv_w[2], conv_w[3], conv_w[4], w2t, w3t, w4t);
  k_block0<<<1000, 256, 0, stream>>>(support, query, conv_w[0], bn_g[0], bn_b[0], a0);
  k_block1<<<250, 256, 0, stream>>>(a0, conv_w[1], bn_g[1], bn_b[1], a1);
  k_conv234<<<250, 256, 0, stream>>>(a1, w2t, bn_g[2], bn_b[2],
                                     w3t, bn_g[3], bn_b[3],
                                     w4t, bn_g[4], bn_b[4], feats);
  k_e<<<100, 256, 0, stream>>>(feats, trans_w, trans_b, e_buf);
  k_routing<<<10, 256, 0, stream>>>(e_buf, proto);
  k_t1<<<100, 256, 0, stream>>>(proto, bil_w, t1);
  k_score<<<1500, 256, 0, stream>>>(t1, feats + 100 * 256, score_w, score_b, s_buf);
  k_lsm<<<1, 256, 0, stream>>>(s_buf, out);
}

// Round 3
// 268.843 us; speedup vs baseline: 4.3639x; 1.2993x over previous
//
#include <hip/hip_runtime.h>
#include <math.h>

// ---------------------------------------------------------------------------
// RoutingNet round 3: batched per-layer conv kernels (occupancy fix for the
// fused conv234, which ran at 1 block/CU = 10% occupancy). Intermediates are
// L2-resident (<=1MB) so unfusing costs no HBM. block1 re-gridded 250->1000.
// t1 split 100->800 blocks with fp32 atomics.
// ---------------------------------------------------------------------------

#define BN_SCALE rsqrtf(1.0f + 1e-5f)

// Transpose w3,w4: OIHW -> [ic][tap][oc]. 73728 + 294912 = 368640 = 1440*256.
__global__ void k_transpose(const float* __restrict__ w3, const float* __restrict__ w4,
                            float* __restrict__ w3t, float* __restrict__ w4t) {
  int i = blockIdx.x * 256 + threadIdx.x;
  if (i < 73728) {                       // w3: OC=128, IC=64
    int oc = i & 127; int r = i >> 7; int tap = r % 9; int ic = r / 9;
    w3t[i] = w3[(oc * 64 + ic) * 9 + tap];
  } else {                               // w4: OC=256, IC=128
    int j = i - 73728;
    int oc = j & 255; int r = j >> 8; int tap = r % 9; int ic = r / 9;
    w4t[j] = w4[(oc * 128 + ic) * 9 + tap];
  }
}

// Block 0: 1->16ch, 128x128 -s2-> 64x64 -pool-> 32x32. Grid 1000 (img x 4 bands).
__global__ void k_block0(const float* __restrict__ sup, const float* __restrict__ qry,
                         const float* __restrict__ w, const float* __restrict__ g,
                         const float* __restrict__ bb, float* __restrict__ out) {
  __shared__ float simg[33 * 128];
  int img = blockIdx.x >> 2, band = blockIdx.x & 3;
  const float* in = (img < 100) ? (sup + (size_t)img * 16384)
                                : (qry + (size_t)(img - 100) * 16384);
  int t = threadIdx.x;
  int row0 = band * 32 - 1;
  for (int i = t; i < 33 * 128; i += 256) {
    int r = i >> 7, cc = i & 127;
    int ry = row0 + r;
    simg[i] = (ry >= 0) ? in[ry * 128 + cc] : 0.f;
  }
  __syncthreads();

  int lane = t & 63, wid = t >> 6;
  int ox = lane & 31, oyh = lane >> 5;
  int oc0 = wid * 4;
  float wv[36], sc[4], bs[4];
#pragma unroll
  for (int j = 0; j < 4; j++) {
#pragma unroll
    for (int k = 0; k < 9; k++) wv[j * 9 + k] = w[(oc0 + j) * 9 + k];
    sc[j] = g[oc0 + j] * BN_SCALE;
    bs[j] = bb[oc0 + j];
  }
#pragma unroll
  for (int oyy = 0; oyy < 4; oyy++) {
    int oy = oyy * 2 + oyh;
    float win[25];
#pragma unroll
    for (int d = 0; d < 5; d++) {
      int lr = 4 * oy + d;
#pragma unroll
      for (int e = 0; e < 5; e++) {
        int cx = 4 * ox - 1 + e;
        win[d * 5 + e] = (cx >= 0) ? simg[lr * 128 + cx] : 0.f;
      }
    }
#pragma unroll
    for (int j = 0; j < 4; j++) {
      float m = -1e30f;
#pragma unroll
      for (int py = 0; py < 2; py++)
#pragma unroll
        for (int px = 0; px < 2; px++) {
          float c = 0.f;
#pragma unroll
          for (int ky = 0; ky < 3; ky++)
#pragma unroll
            for (int kx = 0; kx < 3; kx++)
              c = fmaf(win[(2 * py + ky) * 5 + (2 * px + kx)], wv[j * 9 + ky * 3 + kx], c);
          m = fmaxf(m, fmaf(c, sc[j], bs[j]));
        }
      int OY = band * 8 + oy;
      out[(((size_t)img * 16 + oc0 + j) * 32 + OY) * 32 + ox] = fmaxf(m, 0.f);
    }
  }
}

// Block 1: 16->32ch, 32x32 -s2-> 16x16 -pool-> 8x8.
// Grid 1000: img x 4 pos-quadrants (4x4 pooled each). All 32 oc per block.
__global__ void k_block1(const float* __restrict__ a0, const float* __restrict__ w,
                         const float* __restrict__ g, const float* __restrict__ bb,
                         float* __restrict__ out) {
  __shared__ float sIn[16 * 17 * 18];   // halo-staged, 19.6 KB
  __shared__ float wl[16 * 32 * 12];    // repacked weights, 24.6 KB
  int b = blockIdx.x;
  int img = b >> 2, posq = b & 3;
  int oy0 = (posq >> 1) * 4, ox0 = (posq & 1) * 4;   // pooled-coords origin
  int R0 = 4 * oy0 - 1, C0 = 4 * ox0 - 2;            // input-region origin
  int t = threadIdx.x;
  const float* in = a0 + (size_t)img * 16384;
  for (int i = t; i < 4896; i += 256) {
    int c = i % 18; int rr = (i / 18) % 17; int ic = i / 306;
    int gr = R0 + rr, gc = C0 + c;
    sIn[i] = (gr >= 0 && gc >= 0) ? in[ic * 1024 + gr * 32 + gc] : 0.f;  // gr,gc <= 31
  }
  for (int j = t; j < 4608; j += 256) {
    int tap = j % 9; int r = j / 9; int ocl = r & 31; int ic = r >> 5;
    wl[ic * 384 + ocl * 12 + tap] = w[ocl * 144 + ic * 9 + tap];
  }
  __syncthreads();

  int ocl = t & 15, pos = t >> 4;
  int oyl = pos >> 2, oxl = pos & 3;
  float acc[2][4];
#pragma unroll
  for (int j = 0; j < 2; j++)
#pragma unroll
    for (int p = 0; p < 4; p++) acc[j][p] = 0.f;

  for (int ic = 0; ic < 16; ic++) {
    float win[5][6];
    const float2* base2 = (const float2*)(sIn + ic * 306 + 4 * oyl * 18 + 4 * oxl);
#pragma unroll
    for (int d = 0; d < 5; d++) {
      float2 u = base2[d * 9], v = base2[d * 9 + 1], z = base2[d * 9 + 2];
      win[d][0] = u.x; win[d][1] = u.y; win[d][2] = v.x;
      win[d][3] = v.y; win[d][4] = z.x; win[d][5] = z.y;
    }
#pragma unroll
    for (int j = 0; j < 2; j++) {
      const float* wp = wl + ic * 384 + (ocl + 16 * j) * 12;
      float4 wA = *(const float4*)wp;
      float4 wB = *(const float4*)(wp + 4);
      float w8 = wp[8];
      float wr[9] = {wA.x, wA.y, wA.z, wA.w, wB.x, wB.y, wB.z, wB.w, w8};
#pragma unroll
      for (int py = 0; py < 2; py++)
#pragma unroll
        for (int px = 0; px < 2; px++) {
          float c = acc[j][py * 2 + px];
#pragma unroll
          for (int ky = 0; ky < 3; ky++)
#pragma unroll
            for (int kx = 0; kx < 3; kx++)
              c = fmaf(win[2 * py + ky][1 + 2 * px + kx], wr[ky * 3 + kx], c);
          acc[j][py * 2 + px] = c;
        }
    }
  }
#pragma unroll
  for (int j = 0; j < 2; j++) {
    int oc = ocl + 16 * j;
    float sc = g[oc] * BN_SCALE, bsj = bb[oc];
    float m = -1e30f;
#pragma unroll
    for (int p = 0; p < 4; p++) m = fmaxf(m, fmaf(acc[j][p], sc, bsj));
    out[(size_t)img * 2048 + oc * 64 + (oy0 + oyl) * 8 + (ox0 + oxl)] = fmaxf(m, 0.f);
  }
}

// Layer 2: 32->64ch, 8x8 -> pool 4x4. Grid 1000 (img x 4 oc-quarters).
__global__ void k_conv2(const float* __restrict__ a1, const float* __restrict__ w,
                        const float* __restrict__ g2, const float* __restrict__ b2,
                        float* __restrict__ a2) {
  __shared__ float sA[32 * 100];       // padded 10x10
  __shared__ float wl[32 * 16 * 12];
  int b = blockIdx.x;
  int img = b >> 2, oc0 = (b & 3) * 16;
  int t = threadIdx.x;
  for (int i = t; i < 3200; i += 256) sA[i] = 0.f;
  __syncthreads();
  const float* ap = a1 + (size_t)img * 2048;
  for (int i = t; i < 2048; i += 256) {
    int x = i & 7, y = (i >> 3) & 7, ic = i >> 6;
    sA[ic * 100 + (y + 1) * 10 + (x + 1)] = ap[i];
  }
  for (int j = t; j < 4608; j += 256) {
    int tap = j % 9; int r = j / 9; int ocl = r & 15; int ic = r >> 4;
    wl[ic * 192 + ocl * 12 + tap] = w[(oc0 + ocl) * 288 + ic * 9 + tap];
  }
  __syncthreads();

  int ocl = t & 15, pos = t >> 4;
  int oy = pos >> 2, ox = pos & 3;
  float acc[4] = {0.f, 0.f, 0.f, 0.f};
  for (int ic = 0; ic < 32; ic++) {
    float win[4][4];
    const float2* bse = (const float2*)(sA + ic * 100 + 2 * oy * 10 + 2 * ox);
#pragma unroll
    for (int d = 0; d < 4; d++) {
      float2 u = bse[d * 5], v = bse[d * 5 + 1];
      win[d][0] = u.x; win[d][1] = u.y; win[d][2] = v.x; win[d][3] = v.y;
    }
    const float* wp = wl + ic * 192 + ocl * 12;
    float4 wA = *(const float4*)wp;
    float4 wB = *(const float4*)(wp + 4);
    float w8 = wp[8];
    float wr[9] = {wA.x, wA.y, wA.z, wA.w, wB.x, wB.y, wB.z, wB.w, w8};
#pragma unroll
    for (int py = 0; py < 2; py++)
#pragma unroll
      for (int px = 0; px < 2; px++) {
        float c = acc[py * 2 + px];
#pragma unroll
        for (int ky = 0; ky < 3; ky++)
#pragma unroll
          for (int kx = 0; kx < 3; kx++)
            c = fmaf(win[py + ky][px + kx], wr[ky * 3 + kx], c);
        acc[py * 2 + px] = c;
      }
  }
  int oc = oc0 + ocl;
  float sc = g2[oc] * BN_SCALE, bsj = b2[oc];
  float m = -1e30f;
#pragma unroll
  for (int p = 0; p < 4; p++) m = fmaxf(m, fmaf(acc[p], sc, bsj));
  a2[(size_t)img * 1024 + oc * 16 + oy * 4 + ox] = fmaxf(m, 0.f);
}

// Layer 3: 64->128ch, 4x4 -> pool 2x2. Grid 500 (img x 2 oc-halves).
// Window reads are wave-uniform (lane=oc); weights coalesced from w3t.
__global__ void k_conv3(const float* __restrict__ a2, const float* __restrict__ w3t,
                        const float* __restrict__ g3, const float* __restrict__ b3,
                        float* __restrict__ a3) {
  __shared__ float sB[64 * 36];   // padded 6x6
  int b = blockIdx.x;
  int img = b >> 1, oc0 = (b & 1) * 64;
  int t = threadIdx.x;
  for (int i = t; i < 2304; i += 256) sB[i] = 0.f;
  __syncthreads();
  const float* ap = a2 + (size_t)img * 1024;
  for (int i = t; i < 1024; i += 256) {
    int x = i & 3, y = (i >> 2) & 3, ic = i >> 4;
    sB[ic * 36 + (y + 1) * 6 + (x + 1)] = ap[i];
  }
  __syncthreads();

  int ocl = t & 63, pos = t >> 6;
  int oy = pos >> 1, ox = pos & 1;
  int oc = oc0 + ocl;
  float acc[4] = {0.f, 0.f, 0.f, 0.f};
  for (int ic = 0; ic < 64; ic++) {
    float win[4][4];
    const float2* bse = (const float2*)(sB + ic * 36 + 2 * oy * 6 + 2 * ox);
#pragma unroll
    for (int d = 0; d < 4; d++) {
      float2 u = bse[d * 3], v = bse[d * 3 + 1];
      win[d][0] = u.x; win[d][1] = u.y; win[d][2] = v.x; win[d][3] = v.y;
    }
    const float* wp = w3t + (size_t)ic * 9 * 128 + oc;
    float wr[9];
#pragma unroll
    for (int k = 0; k < 9; k++) wr[k] = wp[k * 128];
#pragma unroll
    for (int py = 0; py < 2; py++)
#pragma unroll
      for (int px = 0; px < 2; px++) {
        float c = acc[py * 2 + px];
#pragma unroll
        for (int ky = 0; ky < 3; ky++)
#pragma unroll
          for (int kx = 0; kx < 3; kx++)
            c = fmaf(win[py + ky][px + kx], wr[ky * 3 + kx], c);
        acc[py * 2 + px] = c;
      }
  }
  float sc = g3[oc] * BN_SCALE, bsj = b3[oc];
  float m = -1e30f;
#pragma unroll
  for (int p = 0; p < 4; p++) m = fmaxf(m, fmaf(acc[p], sc, bsj));
  a3[(size_t)img * 512 + oc * 4 + oy * 2 + ox] = fmaxf(m, 0.f);
}

// Layer 4: 128->256ch, 2x2 -> pool 1x1 -> feats. Grid 500 (img x 2 oc-halves),
// ic split across thread-halves, LDS reduce.
__global__ void k_conv4(const float* __restrict__ a3, const float* __restrict__ w4t,
                        const float* __restrict__ g4, const float* __restrict__ b4,
                        float* __restrict__ feats) {
  __shared__ float sIn[512];
  __shared__ float sP[256 * 4];
  int b = blockIdx.x;
  int img = b >> 1, oc0 = (b & 1) * 128;
  int t = threadIdx.x;
  for (int i = t; i < 512; i += 256) sIn[i] = a3[(size_t)img * 512 + i];
  __syncthreads();

  int ocl = t & 127, ich = t >> 7;
  int oc = oc0 + ocl;
  float acc[4] = {0.f, 0.f, 0.f, 0.f};
  for (int ii = 0; ii < 64; ii++) {
    int ic = ich * 64 + ii;
    float i00 = sIn[ic * 4 + 0], i01 = sIn[ic * 4 + 1];
    float i10 = sIn[ic * 4 + 2], i11 = sIn[ic * 4 + 3];
    const float* wp = w4t + (size_t)ic * 9 * 256 + oc;
    float wr[9];
#pragma unroll
    for (int k = 0; k < 9; k++) wr[k] = wp[k * 256];
#pragma unroll
    for (int py = 0; py < 2; py++)
#pragma unroll
      for (int px = 0; px < 2; px++) {
        float c = acc[py * 2 + px];
        c = fmaf(i00, wr[(1 - py) * 3 + (1 - px)], c);
        c = fmaf(i01, wr[(1 - py) * 3 + (2 - px)], c);
        c = fmaf(i10, wr[(2 - py) * 3 + (1 - px)], c);
        c = fmaf(i11, wr[(2 - py) * 3 + (2 - px)], c);
        acc[py * 2 + px] = c;
      }
  }
#pragma unroll
  for (int p = 0; p < 4; p++) sP[t * 4 + p] = acc[p];
  __syncthreads();
  if (t < 128) {
    int o = oc0 + t;
    float sc = g4[o] * BN_SCALE, bsj = b4[o];
    float m = -1e30f;
#pragma unroll
    for (int p = 0; p < 4; p++)
      m = fmaxf(m, fmaf(sP[t * 4 + p] + sP[(t + 128) * 4 + p], sc, bsj));
    feats[(size_t)img * 256 + o] = fmaxf(m, 0.f);
  }
}

// e[nk,c] = dot(feats[nk,:], trans_w[c,:]) + trans_b[c]. Also zeroes t1.
__global__ void k_e(const float* __restrict__ feats, const float* __restrict__ tw,
                    const float* __restrict__ tb, float* __restrict__ e,
                    float* __restrict__ t1z) {
  for (int i = blockIdx.x * 256 + threadIdx.x; i < 256000; i += 25600) t1z[i] = 0.f;
  int nk = blockIdx.x;
  int c = threadIdx.x;
  __shared__ float sf[256];
  sf[c] = feats[nk * 256 + c];
  __syncthreads();
  const float4* a = (const float4*)(tw + (size_t)c * 256);
  const float4* b = (const float4*)sf;
  float acc = tb[c];
  for (int d = 0; d < 64; d++) {
    float4 x = a[d], y = b[d];
    acc += x.x * y.x + x.y * y.y + x.z * y.z + x.w * y.w;
  }
  e[nk * 256 + c] = acc;
}

// 3-iter routing; one block per n (10 blocks)
__global__ void k_routing(const float* __restrict__ e, float* __restrict__ proto) {
  int n = blockIdx.x;
  __shared__ float se[10 * 256];
  __shared__ float sb[10], sdc[10];
  __shared__ float red[8];
  int t = threadIdx.x;
  int lane = t & 63, wid = t >> 6;
  for (int i = t; i < 2560; i += 256) se[i] = e[n * 2560 + i];
  if (t < 10) sb[t] = 0.f;
  __syncthreads();
  float cd = 0.f;
  for (int iter = 0; iter < 3; iter++) {
    if (t == 0) {
      float mx = sb[0];
      for (int k = 1; k < 10; k++) mx = fmaxf(mx, sb[k]);
      float sum = 0.f;
      for (int k = 0; k < 10; k++) { float ex = expf(sb[k] - mx); sdc[k] = ex; sum += ex; }
      float inv = 1.f / sum;
      for (int k = 0; k < 10; k++) sdc[k] *= inv;
    }
    __syncthreads();
    cd = 0.f;
    for (int k = 0; k < 10; k++) cd = fmaf(sdc[k], se[k * 256 + t], cd);
    float ss = cd * cd;
#pragma unroll
    for (int off = 32; off > 0; off >>= 1) ss += __shfl_down(ss, off, 64);
    if (lane == 0) red[wid] = ss;
    __syncthreads();
    if (t == 0) {
      float tot = red[0] + red[1] + red[2] + red[3];
      red[4] = sqrtf(tot) / (tot + 1.f);
    }
    __syncthreads();
    cd *= red[4];
    __syncthreads();
    for (int k = 0; k < 10; k++) {
      float p = cd * se[k * 256 + t];
#pragma unroll
      for (int off = 32; off > 0; off >>= 1) p += __shfl_down(p, off, 64);
      if (lane == 0) red[wid] = p;
      __syncthreads();
      if (t == 0) sb[k] += red[0] + red[1] + red[2] + red[3];
      __syncthreads();
    }
  }
  proto[n * 256 + t] = cd;
}

// t1[n,h,e] += sum_{c in chunk} proto[n,c] * bil_w[h,c,e]. Grid 800 (h x 8 chunks).
__global__ void k_t1(const float* __restrict__ proto, const float* __restrict__ bw,
                     float* __restrict__ t1) {
  int b = blockIdx.x;
  int h = b >> 3, c0 = (b & 7) * 32;
  int e = threadIdx.x;
  __shared__ float sp[320];
  for (int i = e; i < 320; i += 256) {
    int n = i >> 5, cl = i & 31;
    sp[i] = proto[n * 256 + c0 + cl];
  }
  __syncthreads();
  float acc[10];
#pragma unroll
  for (int n = 0; n < 10; n++) acc[n] = 0.f;
  const float* wp = bw + ((size_t)h * 256 + c0) * 256 + e;
#pragma unroll 4
  for (int cl = 0; cl < 32; cl++) {
    float wv = wp[(size_t)cl * 256];
#pragma unroll
    for (int n = 0; n < 10; n++) acc[n] = fmaf(sp[n * 32 + cl], wv, acc[n]);
  }
#pragma unroll
  for (int n = 0; n < 10; n++)
    atomicAdd(&t1[((size_t)n * 100 + h) * 256 + e], acc[n]);
}

// s[q,n] = sum_h relu(dot(t1[n,h,:], qf[q,:])) * sw[h] + sb
__global__ void k_score(const float* __restrict__ t1, const float* __restrict__ qf,
                        const float* __restrict__ sw, const float* __restrict__ sbp,
                        float* __restrict__ s) {
  int q = blockIdx.x / 10, n = blockIdx.x % 10;
  int t = threadIdx.x, lane = t & 63, wid = t >> 6;
  float qv[4];
#pragma unroll
  for (int j = 0; j < 4; j++) qv[j] = qf[q * 256 + j * 64 + lane];
  const float* tn = t1 + (size_t)n * 100 * 256;
  float acc = 0.f;
  for (int h = wid * 25; h < wid * 25 + 25; h++) {
    float p = 0.f;
#pragma unroll
    for (int j = 0; j < 4; j++) p = fmaf(tn[h * 256 + j * 64 + lane], qv[j], p);
#pragma unroll
    for (int off = 32; off > 0; off >>= 1) p += __shfl_down(p, off, 64);
    if (lane == 0) acc = fmaf(fmaxf(p, 0.f), sw[h], acc);
  }
  __shared__ float r[4];
  if (lane == 0) r[wid] = acc;
  __syncthreads();
  if (t == 0) s[q * 10 + n] = r[0] + r[1] + r[2] + r[3] + sbp[0];
}

__global__ void k_lsm(const float* __restrict__ s, float* __restrict__ out) {
  int q = blockIdx.x * 256 + threadIdx.x;
  if (q >= 150) return;
  float mx = -1e30f;
  for (int n = 0; n < 10; n++) mx = fmaxf(mx, s[q * 10 + n]);
  float sum = 0.f;
  for (int n = 0; n < 10; n++) sum += expf(s[q * 10 + n] - mx);
  float lse = mx + logf(sum);
  for (int n = 0; n < 10; n++) out[q * 10 + n] = s[q * 10 + n] - lse;
}

extern "C" void kernel_launch(void* const* d_in, const int* in_sizes, int n_in,
                              void* d_out, int out_size, void* d_ws, size_t ws_size,
                              hipStream_t stream) {
  const float* support = (const float*)d_in[0];
  const float* query   = (const float*)d_in[1];
  const float* conv_w[5]; const float* bn_g[5]; const float* bn_b[5];
  for (int i = 0; i < 5; i++) {
    conv_w[i] = (const float*)d_in[2 + 3 * i];
    bn_g[i]   = (const float*)d_in[3 + 3 * i];
    bn_b[i]   = (const float*)d_in[4 + 3 * i];
  }
  const float* trans_w = (const float*)d_in[17];
  const float* trans_b = (const float*)d_in[18];
  const float* bil_w   = (const float*)d_in[19];
  const float* score_w = (const float*)d_in[20];
  const float* score_b = (const float*)d_in[21];
  float* out = (float*)d_out;
  float* ws = (float*)d_ws;

  // persistent regions (total 5,040,640 floats = 20.2 MB)
  float* a0    = ws;                 // (250,16,32,32) = 4,096,000
  float* a1    = a0 + 4096000;       // (250,32,8,8)   =   512,000
  float* feats = a1 + 512000;        // (250,256)      =    64,000
  float* w3t   = feats + 64000;      //    73,728
  float* w4t   = w3t + 73728;        //   294,912
  // aliases inside a0 (a0 dead after k_block1):
  float* a2    = a0;                 // (250,64,4,4)  = 256,000
  float* a3    = a0 + 256000;        // (250,128,2,2) = 128,000
  float* e_buf = a0 + 384000;        // (100,256)     =  25,600
  float* proto = a0 + 409600;        // (10,256)      =   2,560
  float* t1    = a0 + 412160;        // (10,100,256)  = 256,000
  float* s_buf = a0 + 668160;        // (150,10)      =   1,500

  k_transpose<<<1440, 256, 0, stream>>>(conv_w[3], conv_w[4], w3t, w4t);
  k_block0<<<1000, 256, 0, stream>>>(support, query, conv_w[0], bn_g[0], bn_b[0], a0);
  k_block1<<<1000, 256, 0, stream>>>(a0, conv_w[1], bn_g[1], bn_b[1], a1);
  k_conv2<<<1000, 256, 0, stream>>>(a1, conv_w[2], bn_g[2], bn_b[2], a2);
  k_conv3<<<500, 256, 0, stream>>>(a2, w3t, bn_g[3], bn_b[3], a3);
  k_conv4<<<500, 256, 0, stream>>>(a3, w4t, bn_g[4], bn_b[4], feats);
  k_e<<<100, 256, 0, stream>>>(feats, trans_w, trans_b, e_buf, t1);
  k_routing<<<10, 256, 0, stream>>>(e_buf, proto);
  k_t1<<<800, 256, 0, stream>>>(proto, bil_w, t1);
  k_score<<<1500, 256, 0, stream>>>(t1, feats + 100 * 256, score_w, score_b, s_buf);
  k_lsm<<<1, 256, 0, stream>>>(s_buf, out);
}